// Round 5
// baseline (1844.320 us; speedup 1.0000x reference)
//
#include <hip/hip_runtime.h>
#include <math.h>

#define BB 64
#define HH 1024
#define VV 32000
#define TT 13
#define QS 8000            // VV/4 per quarter

typedef float f32x4 __attribute__((ext_vector_type(4)));
typedef __bf16 bf16x8 __attribute__((ext_vector_type(8)));

__device__ __forceinline__ unsigned short f2bf(float f) {   // RNE
  unsigned u = __float_as_uint(f);
  u = (u + 0x7fffu + ((u >> 16) & 1u)) >> 16;
  return (unsigned short)u;
}
__device__ __forceinline__ float bf2f(unsigned short s) {
  return __uint_as_float(((unsigned)s) << 16);
}

// ---------------- init: h0/x0 + splits, zero sync counters ----------------
__global__ __launch_bounds__(1024) void k_init(
    const float* __restrict__ enc, const float* __restrict__ emb,
    float* __restrict__ hrm, unsigned short* __restrict__ hhi,
    unsigned short* __restrict__ hlo, unsigned short* __restrict__ xhi,
    unsigned short* __restrict__ xlo, unsigned* __restrict__ gru_arr,
    unsigned* __restrict__ sm_arr) {
  const int g = blockIdx.x * 1024 + threadIdx.x;
  const float h = enc[g];
  hrm[g] = h;
  const unsigned short h16 = f2bf(h);
  hhi[g] = h16;
  hlo[g] = f2bf(h - bf2f(h16));
  float e = emb[threadIdx.x];
  e = e > 0.f ? e : 0.f;
  const unsigned short e16 = f2bf(e);
  xhi[g] = e16;
  xlo[g] = f2bf(e - bf2f(e16));
  if (blockIdx.x == 0) {
    if (threadIdx.x < TT) gru_arr[threadIdx.x] = 0u;
    if (threadIdx.x < TT * BB) sm_arr[threadIdx.x] = 0u;
  }
}

// ---------------- one-time w_out -> bf16 ----------------
__global__ __launch_bounds__(256) void k_wconv(const float* __restrict__ w,
                                               unsigned short* __restrict__ o) {
  const int n4 = VV * HH / 4;
  for (int i = blockIdx.x * 256 + threadIdx.x; i < n4; i += gridDim.x * 256) {
    const f32x4 v = ((const f32x4*)w)[i];
    ushort4 u;
    u.x = f2bf(v[0]); u.y = f2bf(v[1]); u.z = f2bf(v[2]); u.w = f2bf(v[3]);
    ((ushort4*)o)[i] = u;
  }
}

// ---------------- one-time wih/whh -> bf16 hi/lo split ----------------
__global__ __launch_bounds__(256) void k_wconv2(
    const float* __restrict__ wih, const float* __restrict__ whh,
    unsigned short* __restrict__ ghi, unsigned short* __restrict__ glo) {
  const int n4 = 6 * HH * HH / 4;
  for (int i = blockIdx.x * 256 + threadIdx.x; i < n4; i += gridDim.x * 256) {
    const int flat = i * 4;
    const float* src = flat < 3 * HH * HH ? wih + flat : whh + (flat - 3 * HH * HH);
    const f32x4 v = *(const f32x4*)src;
    ushort4 hi, lo;
    hi.x = f2bf(v[0]); lo.x = f2bf(v[0] - bf2f(hi.x));
    hi.y = f2bf(v[1]); lo.y = f2bf(v[1] - bf2f(hi.y));
    hi.z = f2bf(v[2]); lo.z = f2bf(v[2] - bf2f(hi.z));
    hi.w = f2bf(v[3]); lo.w = f2bf(v[3] - bf2f(hi.w));
    ((ushort4*)ghi)[i] = hi;
    ((ushort4*)glo)[i] = lo;
  }
}

// ---------------- fused GRU: split-bf16 MFMA gates (split-K x2) + epilogue ----------------
// grid 768 x 64thr: blk -> (kh = blk&1, g6 = (blk>>1)%6, jt = (blk>>1)/6).
__global__ __launch_bounds__(64) void k_gruF(
    const unsigned short* __restrict__ xhi, const unsigned short* __restrict__ xlo,
    const unsigned short* __restrict__ hhi_s, const unsigned short* __restrict__ hlo_s,
    const unsigned short* __restrict__ ghi, const unsigned short* __restrict__ glo,
    const float* __restrict__ wih, const float* __restrict__ whh,
    const float* __restrict__ bih, const float* __restrict__ bhh,
    const float* __restrict__ hsrc, float* __restrict__ gbuf,
    float* __restrict__ hdst, unsigned short* __restrict__ hhi_d,
    unsigned short* __restrict__ hlo_d, unsigned* __restrict__ gru_arr,
    int t, int cachegw) {
  const int blk = blockIdx.x, lane = threadIdx.x;
  const int kh = blk & 1;
  const int r2 = blk >> 1;
  const int g6 = r2 % 6, jt = r2 / 6;
  const unsigned short* Ahi = g6 < 3 ? xhi : hhi_s;
  const unsigned short* Alo = g6 < 3 ? xlo : hlo_s;
  const int cl = lane & 15, kk = (lane >> 4) * 8;
  const int j = jt * 16 + cl;
  const int kbeg = kh * 512;
  f32x4 acc[4];
  acc[0] = acc[1] = acc[2] = acc[3] = (f32x4){0.f, 0.f, 0.f, 0.f};

  if (cachegw) {
    const unsigned short* bh = ghi + (size_t)(g6 * HH + j) * HH + kbeg;
    const unsigned short* bl = glo + (size_t)(g6 * HH + j) * HH + kbeg;
    const unsigned short* ah = Ahi + kbeg;
    const unsigned short* al = Alo + kbeg;
    #pragma unroll 4
    for (int k0 = 0; k0 < 512; k0 += 32) {
      const bf16x8 whi = *(const bf16x8*)(bh + k0 + kk);
      const bf16x8 wlo = *(const bf16x8*)(bl + k0 + kk);
      #pragma unroll
      for (int rt = 0; rt < 4; ++rt) {
        const size_t aoff = (size_t)(rt * 16 + cl) * HH + k0 + kk;
        const bf16x8 a_h = *(const bf16x8*)(ah + aoff);
        const bf16x8 a_l = *(const bf16x8*)(al + aoff);
        acc[rt] = __builtin_amdgcn_mfma_f32_16x16x32_bf16(a_h, whi, acc[rt], 0, 0, 0);
        acc[rt] = __builtin_amdgcn_mfma_f32_16x16x32_bf16(a_l, whi, acc[rt], 0, 0, 0);
        acc[rt] = __builtin_amdgcn_mfma_f32_16x16x32_bf16(a_h, wlo, acc[rt], 0, 0, 0);
      }
    }
  } else {
    const float* W = (g6 < 3 ? wih : whh) + (size_t)((g6 % 3) * HH + j) * HH + kbeg;
    for (int k0 = 0; k0 < 512; k0 += 32) {
      const f32x4 w0 = *(const f32x4*)(W + k0 + kk);
      const f32x4 w1 = *(const f32x4*)(W + k0 + kk + 4);
      union { unsigned short u[8]; bf16x8 b; } chi, clo;
      #pragma unroll
      for (int u2 = 0; u2 < 4; ++u2) {
        chi.u[u2] = f2bf(w0[u2]); clo.u[u2] = f2bf(w0[u2] - bf2f(chi.u[u2]));
        chi.u[4 + u2] = f2bf(w1[u2]); clo.u[4 + u2] = f2bf(w1[u2] - bf2f(chi.u[4 + u2]));
      }
      #pragma unroll
      for (int rt = 0; rt < 4; ++rt) {
        const size_t aoff = (size_t)(rt * 16 + cl) * HH + kbeg + k0 + kk;
        const bf16x8 a_h = *(const bf16x8*)(Ahi + aoff);
        const bf16x8 a_l = *(const bf16x8*)(Alo + aoff);
        acc[rt] = __builtin_amdgcn_mfma_f32_16x16x32_bf16(a_h, chi.b, acc[rt], 0, 0, 0);
        acc[rt] = __builtin_amdgcn_mfma_f32_16x16x32_bf16(a_l, chi.b, acc[rt], 0, 0, 0);
        acc[rt] = __builtin_amdgcn_mfma_f32_16x16x32_bf16(a_h, clo.b, acc[rt], 0, 0, 0);
      }
    }
  }
  #pragma unroll
  for (int rt = 0; rt < 4; ++rt)
    #pragma unroll
    for (int rg = 0; rg < 4; ++rg) {
      const int row = rt * 16 + (lane >> 4) * 4 + rg;
      gbuf[(size_t)((kh * 6 + g6) * BB + row) * HH + jt * 16 + cl] = acc[rt][rg];
    }

  // ---- device-wide arrive + spin (768 one-wave blocks, all co-resident) ----
  if (lane == 0) {
    __hip_atomic_fetch_add(&gru_arr[t], 1u, __ATOMIC_ACQ_REL, __HIP_MEMORY_SCOPE_AGENT);
    while (__hip_atomic_load(&gru_arr[t], __ATOMIC_ACQUIRE, __HIP_MEMORY_SCOPE_AGENT) < 768u)
      __builtin_amdgcn_s_sleep(4);
  }
  __syncthreads();

  // ---- epilogue: sum partials, nonlinearity, write h + splits ----
  for (int e = blk * 64 + lane; e < BB * HH; e += 768 * 64) {
    const int b = e >> 10, jj = e & (HH - 1);
    const size_t base = (size_t)b * HH + jj;
    const float gir = gbuf[(size_t)(0 * BB + b) * HH + jj] + gbuf[(size_t)((6 + 0) * BB + b) * HH + jj] + bih[jj];
    const float giz = gbuf[(size_t)(1 * BB + b) * HH + jj] + gbuf[(size_t)((6 + 1) * BB + b) * HH + jj] + bih[HH + jj];
    const float gin = gbuf[(size_t)(2 * BB + b) * HH + jj] + gbuf[(size_t)((6 + 2) * BB + b) * HH + jj] + bih[2 * HH + jj];
    const float ghr = gbuf[(size_t)(3 * BB + b) * HH + jj] + gbuf[(size_t)((6 + 3) * BB + b) * HH + jj] + bhh[jj];
    const float ghz = gbuf[(size_t)(4 * BB + b) * HH + jj] + gbuf[(size_t)((6 + 4) * BB + b) * HH + jj] + bhh[HH + jj];
    const float ghn = gbuf[(size_t)(5 * BB + b) * HH + jj] + gbuf[(size_t)((6 + 5) * BB + b) * HH + jj] + bhh[2 * HH + jj];
    const float r_ = 1.f / (1.f + __expf(-(gir + ghr)));
    const float z_ = 1.f / (1.f + __expf(-(giz + ghz)));
    const float n_ = tanhf(gin + r_ * ghn);
    const float hnew = (1.f - z_) * n_ + z_ * hsrc[base];
    hdst[base] = hnew;
    const unsigned short h16 = f2bf(hnew);
    hhi_d[base] = h16;
    hlo_d[base] = f2bf(hnew - bf2f(h16));
  }
}

// ---------------- logits: bf16 MFMA, 500 blocks x 8 waves, split-K x2 ----------------
__global__ __launch_bounds__(512) void k_logits(
    const unsigned short* __restrict__ hb, const unsigned short* __restrict__ wbf,
    const float* __restrict__ wout, const float* __restrict__ bout,
    float* __restrict__ lbuf, int cachew) {
  __shared__ float lacc[4][64][16];
  const int tid = threadIdx.x, blk = blockIdx.x;
  const int lane = tid & 63, wv = tid >> 6;        // 8 waves
  const int cg = wv & 3, kh = wv >> 2;             // colgroup, K-half
  const int n0 = blk * 64 + cg * 16;
  const int cl = lane & 15, kk = (lane >> 4) * 8;
  const int kbeg = kh * 512;
  f32x4 acc[4];
  acc[0] = acc[1] = acc[2] = acc[3] = (f32x4){0.f, 0.f, 0.f, 0.f};

  if (cachew) {
    const unsigned short* wrow = wbf + (size_t)(n0 + cl) * HH + kbeg;
    const unsigned short* arow = hb + kbeg;
    #pragma unroll 2
    for (int k0 = 0; k0 < 512; k0 += 32) {
      const bf16x8 bfr = *(const bf16x8*)(wrow + k0 + kk);
      #pragma unroll
      for (int rt = 0; rt < 4; ++rt) {
        const bf16x8 afr = *(const bf16x8*)(arow + (size_t)(rt * 16 + cl) * HH + k0 + kk);
        acc[rt] = __builtin_amdgcn_mfma_f32_16x16x32_bf16(afr, bfr, acc[rt], 0, 0, 0);
      }
    }
  } else {
    const float* wrow = wout + (size_t)(n0 + cl) * HH + kbeg;
    for (int k0 = 0; k0 < 512; k0 += 32) {
      const f32x4 w0 = *(const f32x4*)(wrow + k0 + kk);
      const f32x4 w1 = *(const f32x4*)(wrow + k0 + kk + 4);
      union { unsigned short u[8]; bf16x8 b; } cv;
      #pragma unroll
      for (int u2 = 0; u2 < 4; ++u2) { cv.u[u2] = f2bf(w0[u2]); cv.u[4 + u2] = f2bf(w1[u2]); }
      #pragma unroll
      for (int rt = 0; rt < 4; ++rt) {
        const bf16x8 afr = *(const bf16x8*)(hb + (size_t)(rt * 16 + cl) * HH + kbeg + k0 + kk);
        acc[rt] = __builtin_amdgcn_mfma_f32_16x16x32_bf16(afr, cv.b, acc[rt], 0, 0, 0);
      }
    }
  }

  if (kh == 1) {
    #pragma unroll
    for (int rt = 0; rt < 4; ++rt)
      *(f32x4*)&lacc[cg][lane][rt * 4] = acc[rt];
  }
  __syncthreads();
  if (kh == 0) {
    const int col = n0 + cl;
    const float bo = bout[col];
    #pragma unroll
    for (int rt = 0; rt < 4; ++rt) {
      const f32x4 o = acc[rt] + *(const f32x4*)&lacc[cg][lane][rt * 4];
      #pragma unroll
      for (int rg = 0; rg < 4; ++rg) {
        const int row = rt * 16 + (lane >> 4) * 4 + rg;
        lbuf[(size_t)row * VV + col] = o[rg] + bo;
      }
    }
  }
}

// ---------------- fused softmax: quarter stats + row sync + out + argmax + next-x ----------------
// grid 256: blk -> (b = blk>>2, q = blk&3). All 256 blocks co-resident.
__global__ __launch_bounds__(256) void k_softmaxF(
    const float* __restrict__ lbuf, const float* __restrict__ wout,
    const float* __restrict__ bout, const float* __restrict__ emb,
    const float* __restrict__ hnew, float* __restrict__ out,
    unsigned short* __restrict__ xhi, unsigned short* __restrict__ xlo,
    float* __restrict__ mq, float* __restrict__ sq, int* __restrict__ candcnt,
    int* __restrict__ candidx, float* __restrict__ candval,
    unsigned* __restrict__ sm_arr, int t) {
  __shared__ float srow[QS];
  __shared__ float red[4];
  __shared__ int icnt, stok;
  const int tid = threadIdx.x;
  const int b = blockIdx.x >> 2, q = blockIdx.x & 3;
  const int lane = tid & 63, wv = tid >> 6;
  const f32x4* src = (const f32x4*)(lbuf + (size_t)b * VV + q * QS);
  f32x4* s4 = (f32x4*)srow;

  // quarter max
  float m = -3.0e38f;
  for (int i = tid; i < QS / 4; i += 256) {
    const f32x4 v = src[i];
    s4[i] = v;
    m = fmaxf(fmaxf(fmaxf(m, v[0]), v[1]), fmaxf(v[2], v[3]));
  }
  #pragma unroll
  for (int d = 1; d < 64; d <<= 1) m = fmaxf(m, __shfl_xor(m, d, 64));
  if (lane == 0) red[wv] = m;
  if (tid == 0) icnt = 0;
  __syncthreads();
  const float M = fmaxf(fmaxf(red[0], red[1]), fmaxf(red[2], red[3]));

  // quarter sumexp
  float s = 0.f;
  for (int i = tid; i < QS / 4; i += 256) {
    const f32x4 v = s4[i];
    s += __expf(v[0] - M) + __expf(v[1] - M) + __expf(v[2] - M) + __expf(v[3] - M);
  }
  #pragma unroll
  for (int d = 1; d < 64; d <<= 1) s += __shfl_xor(s, d, 64);
  __syncthreads();
  if (lane == 0) red[wv] = s;
  __syncthreads();

  // candidates near quarter max
  const float thr = M - 0.05f;
  for (int i = tid; i < QS / 4; i += 256) {
    const f32x4 v = s4[i];
    #pragma unroll
    for (int u = 0; u < 4; ++u)
      if (v[u] >= thr) {
        const int c = atomicAdd(&icnt, 1);
        if (c < 16) {
          candidx[(b * 4 + q) * 16 + c] = q * QS + 4 * i + u;
          candval[(b * 4 + q) * 16 + c] = v[u];
        }
      }
  }
  __syncthreads();
  if (tid == 0) {
    candcnt[b * 4 + q] = icnt < 16 ? icnt : 16;
    mq[b * 4 + q] = M;
    sq[b * 4 + q] = red[0] + red[1] + red[2] + red[3];
    __hip_atomic_fetch_add(&sm_arr[t * BB + b], 1u, __ATOMIC_ACQ_REL, __HIP_MEMORY_SCOPE_AGENT);
    while (__hip_atomic_load(&sm_arr[t * BB + b], __ATOMIC_ACQUIRE, __HIP_MEMORY_SCOPE_AGENT) < 4u)
      __builtin_amdgcn_s_sleep(4);
  }
  __syncthreads();

  // logZ (fixed combine order -> deterministic)
  const float m0 = mq[b * 4 + 0], m1 = mq[b * 4 + 1];
  const float m2 = mq[b * 4 + 2], m3 = mq[b * 4 + 3];
  const float Mg = fmaxf(fmaxf(m0, m1), fmaxf(m2, m3));
  const float Sg = sq[b * 4 + 0] * __expf(m0 - Mg) + sq[b * 4 + 1] * __expf(m1 - Mg) +
                   sq[b * 4 + 2] * __expf(m2 - Mg) + sq[b * 4 + 3] * __expf(m3 - Mg);
  const float LZ = Mg + logf(Sg);

  // out = logits - LZ (from LDS)
  f32x4* dst = (f32x4*)(out + ((size_t)b * TT + t) * VV + q * QS);
  for (int i = tid; i < QS / 4; i += 256)
    dst[i] = s4[i] - LZ;

  if (q == 0 && t < TT - 1) {
    if (tid < 64) {
      const int q2 = tid >> 4, c = tid & 15;
      const int cc = candcnt[b * 4 + q2];
      int vidx = 0;
      bool valid = c < cc;
      if (valid) {
        vidx = candidx[(b * 4 + q2) * 16 + c];
        valid = candval[(b * 4 + q2) * 16 + c] >= Mg - 0.05f;
      }
      unsigned long long mask = __ballot(valid);
      f32x4 h4[4];
      #pragma unroll
      for (int u = 0; u < 4; ++u)
        h4[u] = *(const f32x4*)(hnew + (size_t)b * HH + tid * 16 + u * 4);
      float best = -3.0e38f; int bi = 0x7fffffff;
      while (mask) {
        const int l = __ffsll((unsigned long long)mask) - 1;
        mask &= mask - 1;
        const int v = __shfl(vidx, l, 64);
        const float* wrow = wout + (size_t)v * HH + tid * 16;
        float ss = 0.f;
        #pragma unroll
        for (int u = 0; u < 4; ++u) {
          const f32x4 w4 = *(const f32x4*)(wrow + u * 4);
          ss += h4[u][0] * w4[0] + h4[u][1] * w4[1] + h4[u][2] * w4[2] + h4[u][3] * w4[3];
        }
        #pragma unroll
        for (int d = 1; d < 64; d <<= 1) ss += __shfl_xor(ss, d, 64);
        ss += bout[v];
        if (ss > best || (ss == best && v < bi)) { best = ss; bi = v; }
      }
      if (tid == 0) stok = bi;
    }
    __syncthreads();
    const int tok = stok;
    for (int jj = tid; jj < HH; jj += 256) {
      float e = emb[(size_t)tok * HH + jj];
      e = e > 0.f ? e : 0.f;
      const unsigned short e16 = f2bf(e);
      xhi[(size_t)b * HH + jj] = e16;
      xlo[(size_t)b * HH + jj] = f2bf(e - bf2f(e16));
    }
  }
  if (q == 0 && t == TT - 1) {
    for (int jj = tid; jj < HH; jj += 256)
      out[(size_t)BB * TT * VV + (size_t)b * HH + jj] = hnew[(size_t)b * HH + jj];
  }
}

extern "C" void kernel_launch(void* const* d_in, const int* in_sizes, int n_in,
                              void* d_out, int out_size, void* d_ws, size_t ws_size,
                              hipStream_t stream) {
  const float* enc  = (const float*)d_in[1];
  const float* emb  = (const float*)d_in[2];
  const float* wih  = (const float*)d_in[3];
  const float* whh  = (const float*)d_in[4];
  const float* bih  = (const float*)d_in[5];
  const float* bhh  = (const float*)d_in[6];
  const float* wout = (const float*)d_in[7];
  const float* bout = (const float*)d_in[8];
  float* out = (float*)d_out;

  char* ws = (char*)d_ws;
  size_t off = 0;
  auto alloc = [&](size_t bytes) -> char* {
    char* p = ws + off;
    off += (bytes + 255) & ~(size_t)255;
    return p;
  };
  float* hrm = (float*)alloc((size_t)2 * BB * HH * 4);
  unsigned short* hhi = (unsigned short*)alloc((size_t)2 * BB * HH * 2);
  unsigned short* hlo = (unsigned short*)alloc((size_t)2 * BB * HH * 2);
  unsigned short* xhi = (unsigned short*)alloc((size_t)BB * HH * 2);
  unsigned short* xlo = (unsigned short*)alloc((size_t)BB * HH * 2);
  float* gbuf = (float*)alloc((size_t)12 * BB * HH * 4);
  float* lbuf = (float*)alloc((size_t)BB * VV * 4);
  float* mq = (float*)alloc((size_t)BB * 4 * 4);
  float* sq = (float*)alloc((size_t)BB * 4 * 4);
  int* candcnt = (int*)alloc((size_t)BB * 4 * 4);
  int* candidx = (int*)alloc((size_t)BB * 4 * 16 * 4);
  float* candval = (float*)alloc((size_t)BB * 4 * 16 * 4);
  unsigned* gru_arr = (unsigned*)alloc((size_t)TT * 4);
  unsigned* sm_arr = (unsigned*)alloc((size_t)TT * BB * 4);
  unsigned short* wbf = (unsigned short*)alloc((size_t)VV * HH * 2);
  const int cachew = (ws_size >= off) ? 1 : 0;
  unsigned short* ghi = (unsigned short*)alloc((size_t)6 * HH * HH * 2);
  unsigned short* glo = (unsigned short*)alloc((size_t)6 * HH * HH * 2);
  const int cachegw = (ws_size >= off) ? 1 : 0;

  hipLaunchKernelGGL(k_init, dim3(64), dim3(1024), 0, stream,
                     enc, emb, hrm, hhi, hlo, xhi, xlo, gru_arr, sm_arr);
  if (cachew)
    hipLaunchKernelGGL(k_wconv, dim3(2048), dim3(256), 0, stream, wout, wbf);
  if (cachegw)
    hipLaunchKernelGGL(k_wconv2, dim3(1024), dim3(256), 0, stream, wih, whh, ghi, glo);

  for (int t = 0; t < TT; ++t) {
    const int p = t & 1;
    const float* hsrc = hrm + (size_t)p * BB * HH;
    float* hdst = hrm + (size_t)(p ^ 1) * BB * HH;
    const unsigned short* hhs = hhi + (size_t)p * BB * HH;
    const unsigned short* hls = hlo + (size_t)p * BB * HH;
    unsigned short* hhd = hhi + (size_t)(p ^ 1) * BB * HH;
    unsigned short* hld = hlo + (size_t)(p ^ 1) * BB * HH;

    hipLaunchKernelGGL(k_gruF, dim3(768), dim3(64), 0, stream,
                       xhi, xlo, hhs, hls, ghi, glo, wih, whh, bih, bhh,
                       hsrc, gbuf, hdst, hhd, hld, gru_arr, t, cachegw);
    hipLaunchKernelGGL(k_logits, dim3(500), dim3(512), 0, stream,
                       hhd, wbf, wout, bout, lbuf, cachew);
    hipLaunchKernelGGL(k_softmaxF, dim3(256), dim3(256), 0, stream,
                       lbuf, wout, bout, emb, hdst, out, xhi, xlo,
                       mq, sq, candcnt, candidx, candval, sm_arr, t);
  }
}

// Round 6
// 927.046 us; speedup vs baseline: 1.9895x; 1.9895x over previous
//
#include <hip/hip_runtime.h>
#include <math.h>

#define BB 64
#define HH 1024
#define VV 32000
#define TT 13
#define QS 8000            // VV/4 per quarter
#define BKL 128            // K-tile for staged logits GEMM

typedef float f32x4 __attribute__((ext_vector_type(4)));
typedef __bf16 bf16x8 __attribute__((ext_vector_type(8)));

__device__ __forceinline__ unsigned short f2bf(float f) {   // RNE
  unsigned u = __float_as_uint(f);
  u = (u + 0x7fffu + ((u >> 16) & 1u)) >> 16;
  return (unsigned short)u;
}
__device__ __forceinline__ float bf2f(unsigned short s) {
  return __uint_as_float(((unsigned)s) << 16);
}

// async global->LDS, 16B per lane; LDS dest = wave-uniform base + lane*16
__device__ __forceinline__ void gld16(const void* g, void* l) {
  __builtin_amdgcn_global_load_lds(
      (const __attribute__((address_space(1))) unsigned int*)g,
      (__attribute__((address_space(3))) unsigned int*)l, 16, 0, 0);
}

// ---------------- init ----------------
__global__ __launch_bounds__(1024) void k_init(
    const float* __restrict__ enc, const float* __restrict__ emb,
    float* __restrict__ hrm, unsigned short* __restrict__ hhi,
    unsigned short* __restrict__ hlo, unsigned short* __restrict__ xhi,
    unsigned short* __restrict__ xlo) {
  const int g = blockIdx.x * 1024 + threadIdx.x;
  const float h = enc[g];
  hrm[g] = h;
  const unsigned short h16 = f2bf(h);
  hhi[g] = h16;
  hlo[g] = f2bf(h - bf2f(h16));
  float e = emb[threadIdx.x];
  e = e > 0.f ? e : 0.f;
  const unsigned short e16 = f2bf(e);
  xhi[g] = e16;
  xlo[g] = f2bf(e - bf2f(e16));
}

// ---------------- one-time w_out -> bf16 ----------------
__global__ __launch_bounds__(256) void k_wconv(const float* __restrict__ w,
                                               unsigned short* __restrict__ o) {
  const int n4 = VV * HH / 4;
  for (int i = blockIdx.x * 256 + threadIdx.x; i < n4; i += gridDim.x * 256) {
    const f32x4 v = ((const f32x4*)w)[i];
    ushort4 u;
    u.x = f2bf(v[0]); u.y = f2bf(v[1]); u.z = f2bf(v[2]); u.w = f2bf(v[3]);
    ((ushort4*)o)[i] = u;
  }
}

// ---------------- one-time wih/whh -> bf16 hi/lo split ----------------
__global__ __launch_bounds__(256) void k_wconv2(
    const float* __restrict__ wih, const float* __restrict__ whh,
    unsigned short* __restrict__ ghi, unsigned short* __restrict__ glo) {
  const int n4 = 6 * HH * HH / 4;
  for (int i = blockIdx.x * 256 + threadIdx.x; i < n4; i += gridDim.x * 256) {
    const int flat = i * 4;
    const float* src = flat < 3 * HH * HH ? wih + flat : whh + (flat - 3 * HH * HH);
    const f32x4 v = *(const f32x4*)src;
    ushort4 hi, lo;
    hi.x = f2bf(v[0]); lo.x = f2bf(v[0] - bf2f(hi.x));
    hi.y = f2bf(v[1]); lo.y = f2bf(v[1] - bf2f(hi.y));
    hi.z = f2bf(v[2]); lo.z = f2bf(v[2] - bf2f(hi.z));
    hi.w = f2bf(v[3]); lo.w = f2bf(v[3] - bf2f(hi.w));
    ((ushort4*)ghi)[i] = hi;
    ((ushort4*)glo)[i] = lo;
  }
}

// ---------------- GRU gates: split-bf16 MFMA, split-K x2, 768 one-wave blocks ----------------
// blk -> (kh = blk&1, g6 = (blk>>1)%6, jt = (blk>>1)/6). Writes 12 partial planes.
__global__ __launch_bounds__(64) void k_gru(
    const unsigned short* __restrict__ xhi, const unsigned short* __restrict__ xlo,
    const unsigned short* __restrict__ hhi_s, const unsigned short* __restrict__ hlo_s,
    const unsigned short* __restrict__ ghi, const unsigned short* __restrict__ glo,
    const float* __restrict__ wih, const float* __restrict__ whh,
    float* __restrict__ gbuf, int cachegw) {
  const int blk = blockIdx.x, lane = threadIdx.x;
  const int kh = blk & 1;
  const int r2 = blk >> 1;
  const int g6 = r2 % 6, jt = r2 / 6;
  const unsigned short* Ahi = g6 < 3 ? xhi : hhi_s;
  const unsigned short* Alo = g6 < 3 ? xlo : hlo_s;
  const int cl = lane & 15, kk = (lane >> 4) * 8;
  const int j = jt * 16 + cl;
  const int kbeg = kh * 512;
  f32x4 acc[4];
  acc[0] = acc[1] = acc[2] = acc[3] = (f32x4){0.f, 0.f, 0.f, 0.f};

  if (cachegw) {
    const unsigned short* bh = ghi + (size_t)(g6 * HH + j) * HH + kbeg;
    const unsigned short* bl = glo + (size_t)(g6 * HH + j) * HH + kbeg;
    const unsigned short* ah = Ahi + kbeg;
    const unsigned short* al = Alo + kbeg;
    #pragma unroll 4
    for (int k0 = 0; k0 < 512; k0 += 32) {
      const bf16x8 whi = *(const bf16x8*)(bh + k0 + kk);
      const bf16x8 wlo = *(const bf16x8*)(bl + k0 + kk);
      #pragma unroll
      for (int rt = 0; rt < 4; ++rt) {
        const size_t aoff = (size_t)(rt * 16 + cl) * HH + k0 + kk;
        const bf16x8 a_h = *(const bf16x8*)(ah + aoff);
        const bf16x8 a_l = *(const bf16x8*)(al + aoff);
        acc[rt] = __builtin_amdgcn_mfma_f32_16x16x32_bf16(a_h, whi, acc[rt], 0, 0, 0);
        acc[rt] = __builtin_amdgcn_mfma_f32_16x16x32_bf16(a_l, whi, acc[rt], 0, 0, 0);
        acc[rt] = __builtin_amdgcn_mfma_f32_16x16x32_bf16(a_h, wlo, acc[rt], 0, 0, 0);
      }
    }
  } else {
    const float* W = (g6 < 3 ? wih : whh) + (size_t)((g6 % 3) * HH + j) * HH + kbeg;
    for (int k0 = 0; k0 < 512; k0 += 32) {
      const f32x4 w0 = *(const f32x4*)(W + k0 + kk);
      const f32x4 w1 = *(const f32x4*)(W + k0 + kk + 4);
      union { unsigned short u[8]; bf16x8 b; } chi, clo;
      #pragma unroll
      for (int u2 = 0; u2 < 4; ++u2) {
        chi.u[u2] = f2bf(w0[u2]); clo.u[u2] = f2bf(w0[u2] - bf2f(chi.u[u2]));
        chi.u[4 + u2] = f2bf(w1[u2]); clo.u[4 + u2] = f2bf(w1[u2] - bf2f(chi.u[4 + u2]));
      }
      #pragma unroll
      for (int rt = 0; rt < 4; ++rt) {
        const size_t aoff = (size_t)(rt * 16 + cl) * HH + kbeg + k0 + kk;
        const bf16x8 a_h = *(const bf16x8*)(Ahi + aoff);
        const bf16x8 a_l = *(const bf16x8*)(Alo + aoff);
        acc[rt] = __builtin_amdgcn_mfma_f32_16x16x32_bf16(a_h, chi.b, acc[rt], 0, 0, 0);
        acc[rt] = __builtin_amdgcn_mfma_f32_16x16x32_bf16(a_l, chi.b, acc[rt], 0, 0, 0);
        acc[rt] = __builtin_amdgcn_mfma_f32_16x16x32_bf16(a_h, clo.b, acc[rt], 0, 0, 0);
      }
    }
  }
  #pragma unroll
  for (int rt = 0; rt < 4; ++rt)
    #pragma unroll
    for (int rg = 0; rg < 4; ++rg) {
      const int row = rt * 16 + (lane >> 4) * 4 + rg;
      gbuf[(size_t)((kh * 6 + g6) * BB + row) * HH + jt * 16 + cl] = acc[rt][rg];
    }
}

// ---------------- GRU epilogue: sum split-K partials + nonlinearity + splits ----------------
__global__ __launch_bounds__(256) void k_gep(
    const float* __restrict__ gbuf, const float* __restrict__ bih,
    const float* __restrict__ bhh, const float* __restrict__ hsrc,
    float* __restrict__ hdst, unsigned short* __restrict__ hhi_d,
    unsigned short* __restrict__ hlo_d) {
  const int e = blockIdx.x * 256 + threadIdx.x;       // 256 blocks -> 65536
  const int b = e >> 10, j = e & (HH - 1);
  const size_t base = (size_t)b * HH + j;
  const float gir = gbuf[(size_t)(0 * BB + b) * HH + j] + gbuf[(size_t)((6 + 0) * BB + b) * HH + j] + bih[j];
  const float giz = gbuf[(size_t)(1 * BB + b) * HH + j] + gbuf[(size_t)((6 + 1) * BB + b) * HH + j] + bih[HH + j];
  const float gin = gbuf[(size_t)(2 * BB + b) * HH + j] + gbuf[(size_t)((6 + 2) * BB + b) * HH + j] + bih[2 * HH + j];
  const float ghr = gbuf[(size_t)(3 * BB + b) * HH + j] + gbuf[(size_t)((6 + 3) * BB + b) * HH + j] + bhh[j];
  const float ghz = gbuf[(size_t)(4 * BB + b) * HH + j] + gbuf[(size_t)((6 + 4) * BB + b) * HH + j] + bhh[HH + j];
  const float ghn = gbuf[(size_t)(5 * BB + b) * HH + j] + gbuf[(size_t)((6 + 5) * BB + b) * HH + j] + bhh[2 * HH + j];
  const float r_ = 1.f / (1.f + __expf(-(gir + ghr)));
  const float z_ = 1.f / (1.f + __expf(-(giz + ghz)));
  const float n_ = tanhf(gin + r_ * ghn);
  const float hnew = (1.f - z_) * n_ + z_ * hsrc[base];
  hdst[base] = hnew;
  const unsigned short h16 = f2bf(hnew);
  hhi_d[base] = h16;
  hlo_d[base] = f2bf(hnew - bf2f(h16));
}

// ---------------- logits: m97-style staged GEMM ----------------
// 250 blocks x 512 thr (8 waves, 16 cols/wave). LDS: A/B K-tiles double-buffered,
// global_load_lds with pre-swizzled source, counted vmcnt(6), raw s_barrier.
__global__ __launch_bounds__(512, 1) void k_logits_lds(
    const unsigned short* __restrict__ hb,   // bf16 h [64][1024]
    const unsigned short* __restrict__ wbf,  // bf16 w_out [VV][1024]
    const float* __restrict__ bout, float* __restrict__ lbuf) {
  __shared__ __attribute__((aligned(16))) unsigned char sA[2][64 * BKL * 2];    // 2x16 KB
  __shared__ __attribute__((aligned(16))) unsigned char sB[2][128 * BKL * 2];   // 2x32 KB
  const int tid = threadIdx.x, blk = blockIdx.x;
  const int lane = tid & 63, wv = tid >> 6;
  const int cl = lane & 15, kk = (lane >> 4) * 8;

  // stage one K-tile (A: 16 KB = 2 chunks/thread, B: 32 KB = 4 chunks/thread)
  auto STAGE = [&](int buf, int k0) {
    #pragma unroll
    for (int it = 0; it < 2; ++it) {
      const int c = it * 512 + tid;                  // 16B chunk id
      const int r = c >> 4;                          // A row
      const int kb = (c & 15) * 16;                  // byte-in-row
      const int kbs = kb ^ ((r & 7) << 4);           // inverse swizzle on source
      gld16(hb + (size_t)r * HH + k0 + (kbs >> 1),
            &sA[buf][it * 8192 + wv * 1024]);
    }
    #pragma unroll
    for (int it = 0; it < 4; ++it) {
      const int c = it * 512 + tid;
      const int col = c >> 4;                        // B row (= output col)
      const int kb = (c & 15) * 16;
      const int kbs = kb ^ ((col & 7) << 4);
      gld16(wbf + (size_t)(blk * 128 + col) * HH + k0 + (kbs >> 1),
            &sB[buf][it * 8192 + wv * 1024]);
    }
  };

  f32x4 acc[4];
  acc[0] = acc[1] = acc[2] = acc[3] = (f32x4){0.f, 0.f, 0.f, 0.f};

  STAGE(0, 0);
  for (int t = 0; t < HH / BKL; ++t) {               // 8 K-tiles
    const int cur = t & 1;
    if (t < HH / BKL - 1) {
      STAGE(cur ^ 1, (t + 1) * BKL);
      asm volatile("s_waitcnt vmcnt(6)" ::: "memory");
    } else {
      asm volatile("s_waitcnt vmcnt(0)" ::: "memory");
    }
    __builtin_amdgcn_s_barrier();
    __builtin_amdgcn_sched_barrier(0);
    #pragma unroll
    for (int ks = 0; ks < BKL; ks += 32) {
      const int bc = wv * 16 + cl;
      const bf16x8 bfr = *(const bf16x8*)&sB[cur][bc * (BKL * 2) + (((ks + kk) * 2) ^ ((bc & 7) << 4))];
      #pragma unroll
      for (int rt = 0; rt < 4; ++rt) {
        const int ar = rt * 16 + cl;
        const bf16x8 afr = *(const bf16x8*)&sA[cur][ar * (BKL * 2) + (((ks + kk) * 2) ^ ((ar & 7) << 4))];
        acc[rt] = __builtin_amdgcn_mfma_f32_16x16x32_bf16(afr, bfr, acc[rt], 0, 0, 0);
      }
    }
    __builtin_amdgcn_s_barrier();
    __builtin_amdgcn_sched_barrier(0);
  }

  const int col = blk * 128 + wv * 16 + cl;
  const float bo = bout[col];
  #pragma unroll
  for (int rt = 0; rt < 4; ++rt)
    #pragma unroll
    for (int rg = 0; rg < 4; ++rg) {
      const int row = rt * 16 + (lane >> 4) * 4 + rg;
      lbuf[(size_t)row * VV + col] = acc[rt][rg] + bo;
    }
}

// ---------------- fallback logits (no bf16 cache): round-4 register version ----------------
__global__ __launch_bounds__(256) void k_logits_fb(
    const unsigned short* __restrict__ hb, const float* __restrict__ wout,
    const float* __restrict__ bout, float* __restrict__ lbuf) {
  const int tid = threadIdx.x, blk = blockIdx.x;
  const int lane = tid & 63, wv = tid >> 6;
  const int n0 = blk * 64 + wv * 16;
  const int cl = lane & 15, kk = (lane >> 4) * 8;
  f32x4 acc[4];
  acc[0] = acc[1] = acc[2] = acc[3] = (f32x4){0.f, 0.f, 0.f, 0.f};
  const float* wrow = wout + (size_t)(n0 + cl) * HH;
  for (int k0 = 0; k0 < HH; k0 += 32) {
    const f32x4 w0 = *(const f32x4*)(wrow + k0 + kk);
    const f32x4 w1 = *(const f32x4*)(wrow + k0 + kk + 4);
    union { unsigned short u[8]; bf16x8 b; } cv;
    #pragma unroll
    for (int u2 = 0; u2 < 4; ++u2) { cv.u[u2] = f2bf(w0[u2]); cv.u[4 + u2] = f2bf(w1[u2]); }
    #pragma unroll
    for (int rt = 0; rt < 4; ++rt) {
      const bf16x8 afr = *(const bf16x8*)(hb + (size_t)(rt * 16 + cl) * HH + k0 + kk);
      acc[rt] = __builtin_amdgcn_mfma_f32_16x16x32_bf16(afr, cv.b, acc[rt], 0, 0, 0);
    }
  }
  const int col = n0 + cl;
  const float bo = bout[col];
  #pragma unroll
  for (int rt = 0; rt < 4; ++rt)
    #pragma unroll
    for (int rg = 0; rg < 4; ++rg) {
      const int row = rt * 16 + (lane >> 4) * 4 + rg;
      lbuf[(size_t)row * VV + col] = acc[rt][rg] + bo;
    }
}

// ---------------- quarter stats + per-quarter exact argmax recheck ----------------
// grid 256: blk -> (b = blk>>2, q = blk&3). Exact best per quarter -> qbestV/I.
__global__ __launch_bounds__(256) void k_sum(
    const float* __restrict__ lbuf, const float* __restrict__ wout,
    const float* __restrict__ bout, const float* __restrict__ hnew,
    float* __restrict__ mq, float* __restrict__ sq,
    float* __restrict__ qbestV, int* __restrict__ qbestI, int dorecheck) {
  __shared__ float srow[QS];
  __shared__ float red[4];
  __shared__ int icnt;
  __shared__ int scand[32];
  const int tid = threadIdx.x;
  const int b = blockIdx.x >> 2, q = blockIdx.x & 3;
  const int lane = tid & 63, wv = tid >> 6;
  const f32x4* src = (const f32x4*)(lbuf + (size_t)b * VV + q * QS);
  f32x4* s4 = (f32x4*)srow;

  float m = -3.0e38f;
  for (int i = tid; i < QS / 4; i += 256) {
    const f32x4 v = src[i];
    s4[i] = v;
    m = fmaxf(fmaxf(fmaxf(m, v[0]), v[1]), fmaxf(v[2], v[3]));
  }
  #pragma unroll
  for (int d = 1; d < 64; d <<= 1) m = fmaxf(m, __shfl_xor(m, d, 64));
  if (lane == 0) red[wv] = m;
  if (tid == 0) icnt = 0;
  __syncthreads();
  const float M = fmaxf(fmaxf(red[0], red[1]), fmaxf(red[2], red[3]));

  float s = 0.f;
  for (int i = tid; i < QS / 4; i += 256) {
    const f32x4 v = s4[i];
    s += __expf(v[0] - M) + __expf(v[1] - M) + __expf(v[2] - M) + __expf(v[3] - M);
  }
  #pragma unroll
  for (int d = 1; d < 64; d <<= 1) s += __shfl_xor(s, d, 64);
  __syncthreads();
  if (lane == 0) red[wv] = s;
  __syncthreads();
  if (tid == 0) {
    mq[b * 4 + q] = M;
    sq[b * 4 + q] = red[0] + red[1] + red[2] + red[3];
  }

  if (dorecheck) {
    const float thr = M - 0.05f;                     // quarter band superset of global band
    for (int i = tid; i < QS / 4; i += 256) {
      const f32x4 v = s4[i];
      #pragma unroll
      for (int u = 0; u < 4; ++u)
        if (v[u] >= thr) {
          const int c = atomicAdd(&icnt, 1);
          if (c < 32) scand[c] = q * QS + 4 * i + u;
        }
    }
    __syncthreads();
    if (wv == 0) {                                   // exact f32 recheck, wave 0
      const int nc = icnt < 32 ? icnt : 32;
      const float* hrow = hnew + (size_t)b * HH;
      f32x4 h4[4];
      #pragma unroll
      for (int u = 0; u < 4; ++u) h4[u] = *(const f32x4*)(hrow + lane * 16 + u * 4);
      float best = -3.0e38f; int bi = 0x7fffffff;
      for (int ci = 0; ci < nc; ++ci) {
        const int v = scand[ci];
        const float* wrow = wout + (size_t)v * HH + lane * 16;
        float ss = 0.f;
        #pragma unroll
        for (int u = 0; u < 4; ++u) {
          const f32x4 w4 = *(const f32x4*)(wrow + u * 4);
          ss += h4[u][0] * w4[0] + h4[u][1] * w4[1] + h4[u][2] * w4[2] + h4[u][3] * w4[3];
        }
        #pragma unroll
        for (int d = 1; d < 64; d <<= 1) ss += __shfl_xor(ss, d, 64);
        ss += bout[v];
        if (ss > best || (ss == best && v < bi)) { best = ss; bi = v; }
      }
      if (lane == 0) { qbestV[b * 4 + q] = best; qbestI[b * 4 + q] = bi; }
    }
  }
}

// ---------------- combine + out write + next-x ----------------
// grid 256: blk -> (b, q). q==0 combines 4 exact quarter-bests (tiny).
__global__ __launch_bounds__(256) void k_out(
    const float* __restrict__ lbuf, const float* __restrict__ mq,
    const float* __restrict__ sq, const float* __restrict__ qbestV,
    const int* __restrict__ qbestI, const float* __restrict__ emb,
    const float* __restrict__ hnew, float* __restrict__ out,
    unsigned short* __restrict__ xhi, unsigned short* __restrict__ xlo, int t) {
  __shared__ int stok;
  const int tid = threadIdx.x;
  const int b = blockIdx.x >> 2, q = blockIdx.x & 3;

  const float m0 = mq[b * 4 + 0], m1 = mq[b * 4 + 1];
  const float m2 = mq[b * 4 + 2], m3 = mq[b * 4 + 3];
  const float Mg = fmaxf(fmaxf(m0, m1), fmaxf(m2, m3));
  const float Sg = sq[b * 4 + 0] * __expf(m0 - Mg) + sq[b * 4 + 1] * __expf(m1 - Mg) +
                   sq[b * 4 + 2] * __expf(m2 - Mg) + sq[b * 4 + 3] * __expf(m3 - Mg);
  const float LZ = Mg + logf(Sg);

  const f32x4* src = (const f32x4*)(lbuf + (size_t)b * VV + q * QS);
  f32x4* dst = (f32x4*)(out + ((size_t)b * TT + t) * VV + q * QS);
  for (int i = tid; i < QS / 4; i += 256)
    dst[i] = src[i] - LZ;

  if (q == 0 && t < TT - 1) {
    if (tid == 0) {
      float bv = qbestV[b * 4 + 0]; int bi = qbestI[b * 4 + 0];
      #pragma unroll
      for (int qq = 1; qq < 4; ++qq) {
        const float v = qbestV[b * 4 + qq]; const int i2 = qbestI[b * 4 + qq];
        if (v > bv || (v == bv && i2 < bi)) { bv = v; bi = i2; }
      }
      stok = bi;
    }
    __syncthreads();
    const int tok = stok;
    for (int j = tid; j < HH; j += 256) {
      float e = emb[(size_t)tok * HH + j];
      e = e > 0.f ? e : 0.f;
      const unsigned short e16 = f2bf(e);
      xhi[(size_t)b * HH + j] = e16;
      xlo[(size_t)b * HH + j] = f2bf(e - bf2f(e16));
    }
  }
  if (q == 0 && t == TT - 1) {
    for (int j = tid; j < HH; j += 256)
      out[(size_t)BB * TT * VV + (size_t)b * HH + j] = hnew[(size_t)b * HH + j];
  }
}

extern "C" void kernel_launch(void* const* d_in, const int* in_sizes, int n_in,
                              void* d_out, int out_size, void* d_ws, size_t ws_size,
                              hipStream_t stream) {
  const float* enc  = (const float*)d_in[1];
  const float* emb  = (const float*)d_in[2];
  const float* wih  = (const float*)d_in[3];
  const float* whh  = (const float*)d_in[4];
  const float* bih  = (const float*)d_in[5];
  const float* bhh  = (const float*)d_in[6];
  const float* wout = (const float*)d_in[7];
  const float* bout = (const float*)d_in[8];
  float* out = (float*)d_out;

  char* ws = (char*)d_ws;
  size_t off = 0;
  auto alloc = [&](size_t bytes) -> char* {
    char* p = ws + off;
    off += (bytes + 255) & ~(size_t)255;
    return p;
  };
  float* hrm = (float*)alloc((size_t)2 * BB * HH * 4);
  unsigned short* hhi = (unsigned short*)alloc((size_t)2 * BB * HH * 2);
  unsigned short* hlo = (unsigned short*)alloc((size_t)2 * BB * HH * 2);
  unsigned short* xhi = (unsigned short*)alloc((size_t)BB * HH * 2);
  unsigned short* xlo = (unsigned short*)alloc((size_t)BB * HH * 2);
  float* gbuf = (float*)alloc((size_t)12 * BB * HH * 4);
  float* lbuf = (float*)alloc((size_t)BB * VV * 4);
  float* mq = (float*)alloc((size_t)BB * 4 * 4);
  float* sq = (float*)alloc((size_t)BB * 4 * 4);
  float* qbestV = (float*)alloc((size_t)BB * 4 * 4);
  int* qbestI = (int*)alloc((size_t)BB * 4 * 4);
  unsigned short* wbf = (unsigned short*)alloc((size_t)VV * HH * 2);
  const int cachew = (ws_size >= off) ? 1 : 0;
  unsigned short* ghi = (unsigned short*)alloc((size_t)6 * HH * HH * 2);
  unsigned short* glo = (unsigned short*)alloc((size_t)6 * HH * HH * 2);
  const int cachegw = (ws_size >= off) ? 1 : 0;

  hipLaunchKernelGGL(k_init, dim3(64), dim3(1024), 0, stream,
                     enc, emb, hrm, hhi, hlo, xhi, xlo);
  if (cachew)
    hipLaunchKernelGGL(k_wconv, dim3(2048), dim3(256), 0, stream, wout, wbf);
  if (cachegw)
    hipLaunchKernelGGL(k_wconv2, dim3(1024), dim3(256), 0, stream, wih, whh, ghi, glo);

  for (int t = 0; t < TT; ++t) {
    const int p = t & 1;
    const float* hsrc = hrm + (size_t)p * BB * HH;
    float* hdst = hrm + (size_t)(p ^ 1) * BB * HH;
    const unsigned short* hhs = hhi + (size_t)p * BB * HH;
    const unsigned short* hls = hlo + (size_t)p * BB * HH;
    unsigned short* hhd = hhi + (size_t)(p ^ 1) * BB * HH;
    unsigned short* hld = hlo + (size_t)(p ^ 1) * BB * HH;

    hipLaunchKernelGGL(k_gru, dim3(768), dim3(64), 0, stream,
                       xhi, xlo, hhs, hls, ghi, glo, wih, whh, gbuf, cachegw);
    hipLaunchKernelGGL(k_gep, dim3(256), dim3(256), 0, stream,
                       gbuf, bih, bhh, hsrc, hdst, hhd, hld);
    if (cachew)
      hipLaunchKernelGGL(k_logits_lds, dim3(250), dim3(512), 0, stream,
                         hhd, wbf, bout, lbuf);
    else
      hipLaunchKernelGGL(k_logits_fb, dim3(500), dim3(256), 0, stream,
                         hhd, wout, bout, lbuf);
    hipLaunchKernelGGL(k_sum, dim3(256), dim3(256), 0, stream,
                       lbuf, wout, bout, hdst, mq, sq, qbestV, qbestI,
                       (t < TT - 1) ? 1 : 0);
    hipLaunchKernelGGL(k_out, dim3(256), dim3(256), 0, stream,
                       lbuf, mq, sq, qbestV, qbestI, emb, hdst, out, xhi, xlo, t);
  }
}